// Round 1
// baseline (330.150 us; speedup 1.0000x reference)
//
#include <hip/hip_runtime.h>

// Problem constants
#define BSZ    8192
#define NWRD   4
#define SEQL   16
#define EDIM   128
#define HDIM   128
#define VOCAB  64
#define GDIM   512      // 4*H
#define MSEQ   32       // sequences per workgroup

typedef float  f32x4  __attribute__((ext_vector_type(4)));
typedef float  f32x16 __attribute__((ext_vector_type(16)));
typedef __bf16 bf16x8 __attribute__((ext_vector_type(8)));

__device__ __forceinline__ unsigned short f2bf(float f) {
    unsigned int u = __builtin_bit_cast(unsigned int, f);
    return (unsigned short)((u + 0x7fff + ((u >> 16) & 1)) >> 16);  // RNE
}
__device__ __forceinline__ float sigm(float x) {
    return __fdividef(1.f, 1.f + __expf(-x));
}
__device__ __forceinline__ float tanhx(float x) {
    return __fdividef(2.f, 1.f + __expf(-2.f * x)) - 1.f;
}

// ---------------------------------------------------------------------------
// P2[v][j][g] = b_ih[g*128+j] + b_hh[g*128+j] + sum_e emb[v][e] * W_ih[g*128+j][e]
// Folds the entire input-side GEMM + both biases into a 64x128x4 fp32 table.
// ---------------------------------------------------------------------------
__global__ void prep_P(const float* __restrict__ emb, const float* __restrict__ W_ih,
                       const float* __restrict__ b_ih, const float* __restrict__ b_hh,
                       float* __restrict__ P2)
{
    int idx = blockIdx.x * 256 + threadIdx.x;      // 8192 = v*128 + j
    int v = idx >> 7, j = idx & 127;
    f32x4 r;
#pragma unroll
    for (int g = 0; g < 4; ++g) {
        int n = g * 128 + j;
        float s = b_ih[n] + b_hh[n];
        for (int e = 0; e < 128; e += 4) {
            s += emb[v*128 + e + 0] * W_ih[n*128 + e + 0];
            s += emb[v*128 + e + 1] * W_ih[n*128 + e + 1];
            s += emb[v*128 + e + 2] * W_ih[n*128 + e + 2];
            s += emb[v*128 + e + 3] * W_ih[n*128 + e + 3];
        }
        r[g] = s;
    }
    *(f32x4*)(P2 + idx * 4) = r;
}

// ---------------------------------------------------------------------------
// W_hh -> bf16, B-fragment order for mfma_f32_32x32x16_bf16:
// WF[((nt*8+kc)*64 + l)*8 + jj] = B[k][n] = W_hh[n][k]
//   n = nt*32 + (l&31),  k = kc*16 + (l>>5)*8 + jj
// ---------------------------------------------------------------------------
__global__ void prep_W(const float* __restrict__ W_hh, unsigned short* __restrict__ WF)
{
    int idx = blockIdx.x * 256 + threadIdx.x;      // 65536
    int jj = idx & 7, l = (idx >> 3) & 63, kc = (idx >> 9) & 7, nt = idx >> 12;
    int n = nt * 32 + (l & 31);
    int k = kc * 16 + (l >> 5) * 8 + jj;
    WF[idx] = f2bf(W_hh[n * 128 + k]);
}

// ---------------------------------------------------------------------------
// Fused LSTM(16 steps, MFMA) + gram/cosine + conv1 + conv2 + scorer + sigmoid.
// 1 WG = 32 sequences = 8 batches. Wave w owns gate cols {g*128 + 32w}.
// ---------------------------------------------------------------------------
__global__ __launch_bounds__(256, 2) void lstm_fused(
    const int* __restrict__ word_ids, const int* __restrict__ lengths,
    const float* __restrict__ conv1_w, const float* __restrict__ conv1_b,
    const float* __restrict__ conv2_w, const float* __restrict__ conv2_b,
    const float* __restrict__ scorer_w, const float* __restrict__ scorer_b,
    const float* __restrict__ P2, const unsigned short* __restrict__ WF,
    float* __restrict__ out)
{
    __shared__ __align__(16) unsigned short h_frag[8 * 64 * 8];  // A-fragment order, 8KB
    __shared__ __align__(16) float reps[MSEQ * HDIM];            // 16KB (c states)
    __shared__ int   words_s[MSEQ * SEQL];
    __shared__ int   len_s[MSEQ];
    __shared__ float gram_s[8 * 16];

    const int tid    = threadIdx.x;
    const int wv     = tid >> 6;        // wave 0..3
    const int lane   = tid & 63;
    const int lane31 = lane & 31;
    const int half   = lane >> 5;
    const int seq0   = blockIdx.x * MSEQ;

    // B fragments (W_hh) in registers: wave wv needs nt = g*4 + wv (cols g*128+32*wv)
    bf16x8 bfr[4][8];
#pragma unroll
    for (int g = 0; g < 4; ++g)
#pragma unroll
        for (int kc = 0; kc < 8; ++kc) {
            int nt = g * 4 + wv;
            bfr[g][kc] = *(const bf16x8*)(WF + ((nt * 8 + kc) * 64 + lane) * 8);
        }

    for (int i = tid; i < MSEQ * SEQL; i += 256) {
        int m = i >> 4, t = i & 15;
        words_s[i] = word_ids[(seq0 + m) * SEQL + t];
    }
    if (tid < MSEQ) len_s[tid] = lengths[seq0 + tid];
    for (int i = tid; i < 2048; i += 256) ((int*)h_frag)[i] = 0;   // h0 = 0
    __syncthreads();

    const int rbase = half * 4;              // C/D row = (r&3) + 8*(r>>2) + rbase
    int lenr[16];
#pragma unroll
    for (int r = 0; r < 16; ++r)
        lenr[r] = len_s[rbase + (r & 3) + 8 * (r >> 2)];

    const int jcol = wv * 32 + lane31;       // h/c column this lane owns
    // LDS offset for writing h[m][jcol] in A-fragment order
    const int hoff = ((jcol >> 4) * 64 + ((jcol >> 3) & 1) * 32) * 8 + (jcol & 7);

    f32x16 c;
#pragma unroll
    for (int r = 0; r < 16; ++r) c[r] = 0.f;

    for (int t = 0; t < SEQL; ++t) {
        // gate accumulators initialized from the precomputed P table (x@W_ih^T + biases)
        f32x16 acc[4];
#pragma unroll
        for (int r = 0; r < 16; ++r) {
            int m = rbase + (r & 3) + 8 * (r >> 2);
            int w = words_s[m * SEQL + t];
            const f32x4 p = *(const f32x4*)(P2 + (w * HDIM + jcol) * 4);
            acc[0][r] = p.x; acc[1][r] = p.y; acc[2][r] = p.z; acc[3][r] = p.w;
        }

        // A fragments: h from LDS (read before writes of this step; barrier orders them)
        bf16x8 afr[8];
#pragma unroll
        for (int kc = 0; kc < 8; ++kc)
            afr[kc] = *(const bf16x8*)(&h_frag[(kc * 64 + lane) * 8]);
        __syncthreads();

#pragma unroll
        for (int kc = 0; kc < 8; ++kc)
#pragma unroll
            for (int g = 0; g < 4; ++g)
                acc[g] = __builtin_amdgcn_mfma_f32_32x32x16_bf16(afr[kc], bfr[g][kc], acc[g], 0, 0, 0);

#pragma unroll
        for (int r = 0; r < 16; ++r) {
            int m = rbase + (r & 3) + 8 * (r >> 2);
            float ig = sigm(acc[0][r]);
            float fg = sigm(acc[1][r]);
            float gg = tanhx(acc[2][r]);
            float og = sigm(acc[3][r]);
            float cn = fg * c[r] + ig * gg;
            float hn = og * tanhx(cn);
            if (t < lenr[r]) {               // masked rows: freeze by skipping the update
                c[r] = cn;
                h_frag[hoff + m * 8] = f2bf(hn);
            }
        }
        __syncthreads();
    }

    // reps = final cell state c
#pragma unroll
    for (int r = 0; r < 16; ++r) {
        int m = rbase + (r & 3) + 8 * (r >> 2);
        reps[m * HDIM + jcol] = c[r];
    }
    __syncthreads();

    // ---- epilogue: per batch (8 per WG) gram -> cosine -> conv1 -> conv2 -> score ----
    const int bt  = tid >> 5;   // 0..7
    const int sub = tid & 31;

    float dval = 0.f;
    if (sub < 16) {
        int i = sub >> 2, j = sub & 3;
        const f32x4* ci = (const f32x4*)(reps + (bt * 4 + i) * HDIM);
        const f32x4* cj = (const f32x4*)(reps + (bt * 4 + j) * HDIM);
        f32x4 s4 = {0.f, 0.f, 0.f, 0.f};
        for (int k = 0; k < HDIM / 4; ++k) s4 += ci[k] * cj[k];
        dval = s4.x + s4.y + s4.z + s4.w;
        gram_s[bt * 16 + sub] = dval;
    }
    __syncthreads();
    float cosv = 0.f;
    if (sub < 16) {
        int i = sub >> 2, j = sub & 3;
        float di = gram_s[bt * 16 + i * 4 + i];
        float dj = gram_s[bt * 16 + j * 4 + j];
        cosv = __fdividef(dval, sqrtf(di * dj));
    }
    __syncthreads();
    if (sub < 16) gram_s[bt * 16 + sub] = cosv;
    __syncthreads();

    if (sub == 0) {
        float img[4][4];
#pragma unroll
        for (int i = 0; i < 4; ++i)
#pragma unroll
            for (int j = 0; j < 4; ++j) img[i][j] = gram_s[bt * 16 + i * 4 + j];

        float o1[4][3][3];
#pragma unroll
        for (int ch = 0; ch < 4; ++ch) {
            float w00 = conv1_w[ch*4+0], w01 = conv1_w[ch*4+1];
            float w10 = conv1_w[ch*4+2], w11 = conv1_w[ch*4+3];
            float bb  = conv1_b[ch];
#pragma unroll
            for (int y = 0; y < 3; ++y)
#pragma unroll
                for (int x = 0; x < 3; ++x) {
                    float s = bb + w00*img[y][x]   + w01*img[y][x+1]
                                 + w10*img[y+1][x] + w11*img[y+1][x+1];
                    o1[ch][y][x] = s > 0.f ? s : 0.f;
                }
        }
        float sc = scorer_b[0];
#pragma unroll
        for (int oc = 0; oc < 8; ++oc) {
            float bb = conv2_b[oc];
#pragma unroll
            for (int y = 0; y < 2; ++y)
#pragma unroll
                for (int x = 0; x < 2; ++x) {
                    float s = bb;
#pragma unroll
                    for (int ic = 0; ic < 4; ++ic) {
                        const float* w = conv2_w + oc * 16 + ic * 4;
                        s += w[0]*o1[ic][y][x]   + w[1]*o1[ic][y][x+1]
                           + w[2]*o1[ic][y+1][x] + w[3]*o1[ic][y+1][x+1];
                    }
                    float rl = s > 0.f ? s : 0.f;
                    sc += rl * scorer_w[oc * 4 + y * 2 + x];   // flat idx = oc*4+y*2+x
                }
        }
        out[blockIdx.x * 8 + bt] = sigm(sc);
    }
}

extern "C" void kernel_launch(void* const* d_in, const int* in_sizes, int n_in,
                              void* d_out, int out_size, void* d_ws, size_t ws_size,
                              hipStream_t stream)
{
    const int*   word_ids = (const int*)d_in[0];
    const int*   lengths  = (const int*)d_in[1];
    const float* emb      = (const float*)d_in[2];
    const float* W_ih     = (const float*)d_in[3];
    const float* W_hh     = (const float*)d_in[4];
    const float* b_ih     = (const float*)d_in[5];
    const float* b_hh     = (const float*)d_in[6];
    const float* conv1_w  = (const float*)d_in[7];
    const float* conv1_b  = (const float*)d_in[8];
    const float* conv2_w  = (const float*)d_in[9];
    const float* conv2_b  = (const float*)d_in[10];
    const float* scorer_w = (const float*)d_in[11];
    const float* scorer_b = (const float*)d_in[12];
    float* out = (float*)d_out;

    float* P2 = (float*)d_ws;                                        // 128 KB
    unsigned short* WF = (unsigned short*)((char*)d_ws + 64*128*4*4); // 128 KB

    prep_P<<<32, 256, 0, stream>>>(emb, W_ih, b_ih, b_hh, P2);
    prep_W<<<256, 256, 0, stream>>>(W_hh, WF);
    lstm_fused<<<1024, 256, 0, stream>>>(word_ids, lengths,
        conv1_w, conv1_b, conv2_w, conv2_b, scorer_w, scorer_b, P2, WF, out);
}